// Round 5
// baseline (3485.031 us; speedup 1.0000x reference)
//
#include <hip/hip_runtime.h>

// Seq2seq LSTM (B=64, T=256, E=512, H=1024, V_TGT=64) on gfx950.
//   k1a: gather+convert A_bf16[16512][512]
//   k1w: W_lstm fp32 [1536][4096] -> WpermT bf16 [4096][1536] (col-permuted)
//   k1p: W_proj -> WprojT bf16 [64][1024]
//   k2 : Zx bf16 [16512][4096] = A @ Wx
//   k3 : persistent recurrence, 4 independent per-bg chains.
//        Round-11: XCD-LOCAL chains. Rounds 6-10 showed step time is pinned
//        at ~5.5us for EVERY agent-scope barrier design -> the bottleneck is
//        the MALL transport (~1000cy/hop), not the protocol. Now chain c =
//        w%8 (empirical round-robin WG->XCD), 512 WGs launched, XCDs 4-7
//        exit. Startup handshake: each WG publishes its HW XCC_ID; each
//        chain verifies all 64 members share one XCD -> per-chain `fast`
//        flag (members agree: same 64 directory entries).
//        fast: h-stores PLAIN (write-through to local L2), slot publish
//              PLAIN, polls via sc0 loads (L1-bypass, L2-hit ~250cy), h
//              loads plain (L1 staleness impossible: rotating buffers cycle
//              the 32KB L1 every step; chainD/hbuf1 write-once).
//        slow: the r10 agent-scope protocol, bit-identical. Correctness
//              never depends on the WG->XCD mapping (G16).
//        Slots at 128B stride (sole writer/line); producer-major h slabs
//        (sole writer lines, coalesced consumer frags); overlay-safety by
//        publish-after-drain, unchanged.
//        Lessons kept: r8 = never interleave polls with in-flight loads;
//        r9 = phase-interleaved chains serialize.
//   k4 : projection + softmax -> d_out fp32 [64][256][64]

typedef __attribute__((ext_vector_type(8))) short short8;        // bf16 frag
typedef __attribute__((ext_vector_type(4))) float f32x4;         // MFMA acc
typedef __attribute__((ext_vector_type(4))) float float4v;
typedef __attribute__((ext_vector_type(4))) unsigned short ushort4v;

#define MFMA16(A, B, C) __builtin_amdgcn_mfma_f32_16x16x32_bf16((A), (B), (C), 0, 0, 0)
#define WAIT_VM0() __builtin_amdgcn_s_waitcnt(0x0F70)   // vmcnt(0), ignore exp/lgkm
#define COMPILER_FENCE() asm volatile("" ::: "memory")

__device__ __forceinline__ unsigned short f2bf(float f) {
  union { float f; unsigned u; } v; v.f = f;
  unsigned r = (v.u + 0x7fffu + ((v.u >> 16) & 1u)) >> 16;   // RNE, no NaN in data
  return (unsigned short)r;
}
__device__ __forceinline__ float bf2f(unsigned short h) {
  union { unsigned u; float f; } v; v.u = ((unsigned)h) << 16;
  return v.f;
}
__device__ __forceinline__ float sigf(float x) { return 1.0f / (1.0f + __expf(-x)); }
__device__ __forceinline__ float tanhf_fast(float x) { return 1.0f - 2.0f / (1.0f + __expf(2.0f * x)); }

// L1-bypass, L2-visible poll load (fast path): sc0 only.
__device__ __forceinline__ int load_sc0(const int* p) {
  int v;
  asm volatile("global_load_dword %0, %1, off sc0\n\t"
               "s_waitcnt vmcnt(0)"
               : "=v"(v) : "v"(p) : "memory");
  return v;
}

// Chain slab for chain c at step t (h consumed at step t), PRODUCER-MAJOR:
// 64 blocks x 512B; block ug = [16 rows][16 units] (row-major inside block).
//   t==1      : hbuf1 + c*16384 shorts
//   2..256    : overlay dead Zx rows (t-2)*64 + 16c..+15 (consumed by chain c
//               itself at step t-2; publish-after-drain makes this safe)
//   257..512  : chainD + (t-257)*65536 + c*16384 (k4's input)
__device__ __forceinline__ unsigned short*
chain_slab(unsigned short* Zx, unsigned short* hbuf1, unsigned short* chainD,
           int t, int c)
{
  if (t == 1)  return hbuf1 + c * 16384;
  if (t < 257) return Zx + (size_t)(t - 2) * 262144 + c * 65536;
  return chainD + (size_t)(t - 257) * 65536 + c * 16384;
}

// ---------------------------------------------------------------- k1a
__global__ __launch_bounds__(128)
void k1a_gather(const int* __restrict__ tok_src,
                const float* __restrict__ emb_src,
                const float* __restrict__ emb_tgt,
                unsigned short* __restrict__ A)
{
  const int n = blockIdx.x;     // 0..16511
  const int i = threadIdx.x;    // 0..127, each does 4 elements
  float4v v = {0.f, 0.f, 0.f, 0.f};
  if (n < 16384) {
    const int b = n & 63, t = n >> 6;                 // row n = t*64 + b
    const int tk = tok_src[b * 256 + t];              // input_source[b][t]
    v = *(const float4v*)(emb_src + (size_t)tk * 512 + i * 4);
  } else if (n < 16448) {
    v = *(const float4v*)(emb_tgt + (size_t)(n - 16384) * 512 + i * 4);
  }
  ushort4v o;
  o.x = f2bf(v.x); o.y = f2bf(v.y); o.z = f2bf(v.z); o.w = f2bf(v.w);
  *(ushort4v*)(A + (size_t)n * 512 + i * 4) = o;
}

// ---------------------------------------------------------------- k1w
__global__ __launch_bounds__(256)
void k1w_perm(const float* __restrict__ W, unsigned short* __restrict__ WT)
{
  const int id = blockIdx.x * 256 + threadIdx.x;  // < 786432 = 4096 * 192
  const int n  = id & 4095;                        // permuted col
  const int k0 = (id >> 12) * 8;                   // 0..1528
  const int g = n & 3, u = (n >> 2) & 3, wq = n >> 4;
  const int oc = g * 1024 + 4 * wq + u;
  short8 o;
#pragma unroll
  for (int j = 0; j < 8; ++j)
    o[j] = (short)f2bf(W[(size_t)(k0 + j) * 4096 + oc]);
  *(short8*)(WT + (size_t)n * 1536 + k0) = o;
}

// ---------------------------------------------------------------- k1p
__global__ __launch_bounds__(256)
void k1p_perm(const float* __restrict__ W, unsigned short* __restrict__ WT)
{
  const int id = blockIdx.x * 256 + threadIdx.x;  // < 8192 = 64 * 128
  const int n  = id & 63;
  const int k0 = (id >> 6) * 8;
  short8 o;
#pragma unroll
  for (int j = 0; j < 8; ++j)
    o[j] = (short)f2bf(W[(size_t)(k0 + j) * 64 + n]);
  *(short8*)(WT + (size_t)n * 1024 + k0) = o;
}

// ---------------------------------------------------------------- k2
__global__ __launch_bounds__(256, 1)
void k2_gemm(const unsigned short* __restrict__ A,
             const unsigned short* __restrict__ BT,
             unsigned short* __restrict__ C)
{
  __shared__ __align__(16) unsigned short As[128 * 40];
  __shared__ __align__(16) unsigned short Bs[128 * 40];
  const int tid = threadIdx.x;
  const int n0 = blockIdx.x * 128;   // 32 blocks
  const int m0 = blockIdx.y * 128;   // 129 blocks
  const int wv = tid >> 6, lane = tid & 63;
  const int wr = wv & 1, wc = wv >> 1;
  const int q = lane >> 4, l15 = lane & 15;
  f32x4 acc[4][4];
#pragma unroll
  for (int a = 0; a < 4; ++a)
#pragma unroll
    for (int b = 0; b < 4; ++b)
      acc[a][b] = (f32x4){0.f, 0.f, 0.f, 0.f};

  for (int kt = 0; kt < 16; ++kt) {   // K = 512, BK = 32
    __syncthreads();
#pragma unroll
    for (int s = 0; s < 2; ++s) {
      const int ci = tid + s * 256;
      const int row = ci >> 2, kc = ci & 3;
      *(short8*)(&As[row * 40 + kc * 8]) =
          *(const short8*)(A + (size_t)(m0 + row) * 512 + kt * 32 + kc * 8);
      *(short8*)(&Bs[row * 40 + kc * 8]) =
          *(const short8*)(BT + (size_t)(n0 + row) * 1536 + kt * 32 + kc * 8);
    }
    __syncthreads();
    short8 af[4], bf[4];
#pragma unroll
    for (int i = 0; i < 4; ++i) {
      af[i] = *(const short8*)(&As[(wr * 64 + i * 16 + l15) * 40 + q * 8]);
      bf[i] = *(const short8*)(&Bs[(wc * 64 + i * 16 + l15) * 40 + q * 8]);
    }
#pragma unroll
    for (int mi = 0; mi < 4; ++mi)
#pragma unroll
      for (int ni = 0; ni < 4; ++ni)
        acc[mi][ni] = MFMA16(af[mi], bf[ni], acc[mi][ni]);
  }
#pragma unroll
  for (int mi = 0; mi < 4; ++mi)
#pragma unroll
    for (int ni = 0; ni < 4; ++ni)
#pragma unroll
      for (int i = 0; i < 4; ++i) {
        const int row = m0 + wr * 64 + mi * 16 + q * 4 + i;
        const int col = n0 + wc * 64 + ni * 16 + l15;
        C[(size_t)row * 4096 + col] = f2bf(acc[mi][ni][i]);
      }
}

// ---------------------------------------------------------------- k3
// 512 WGs x 256 threads; WGs with (w&7)>=4 exit. chain bg = w&7 (one XCD
// under round-robin mapping), ug = w>>3 in 0..63. Wave wv -> unit-quad
// Q = 4*ug + wv. Slot[bg][ug] at 128B stride (sole writer per line).
__global__ __launch_bounds__(256, 1)
void k3_rnn(unsigned short* __restrict__ Zx,
            const unsigned short* __restrict__ WT,
            const float* __restrict__ b_lstm,
            const int* __restrict__ tok_tgt,
            unsigned short* __restrict__ hbuf1,    // C_1 (128 KB)
            unsigned short* __restrict__ chainD,   // C_257..C_512 (32 MB)
            int* __restrict__ slot,                // [4][64] counters, 128B stride
            int* __restrict__ dir)                 // [512] XCC_ID+1 directory
{
  __shared__ float ztile[4 * 16 * 17];             // per-wave 16x16 (+1 pad)
  __shared__ int s_fast;
  const int w = blockIdx.x;
  const int bg = w & 7;                        // chain / expected XCD
  if (bg >= 4) return;                         // spare half of the grid
  const int tid = threadIdx.x;
  const int wv = tid >> 6, lane = tid & 63;
  const int ug = w >> 3;                       // unit group 0..63
  const int Q  = 4 * ug + wv;                  // this wave's unit-quad (0..255)
  int* const slot_bg = slot + bg * 2048;       // 64 slots, 32-int (128B) stride

  // Gate-phase lane mapping: 64 lanes = 16 rows x 4 units.
  const int gr = lane >> 2, gu = lane & 3;
  const int rglob = bg * 16 + gr;
  const float bias0 = b_lstm[4 * Q + gu];                  // i
  const float bias1 = b_lstm[1024 + 4 * Q + gu];           // j
  const float bias2 = b_lstm[2048 + 4 * Q + gu] + 1.0f;    // f + forget_bias
  const float bias3 = b_lstm[3072 + 4 * Q + gu];           // o
  float cst = 0.f;
  // MFMA-phase lane mapping.
  const int q = lane >> 4, m15 = lane & 15;
  float* const zt_w = &ztile[wv * 272];

  // Wave's W_h B-frags: col Q*16+m15, k 512+kt*32+q*8.
  short8 Breg[32];
  {
    const unsigned short* wsrc = WT + (size_t)(Q * 16 + m15) * 1536 + 512 + q * 8;
#pragma unroll
    for (int kt = 0; kt < 32; ++kt)
      Breg[kt] = *(const short8*)(wsrc + kt * 32);
  }

  // ---- One-time XCD discovery: is this chain entirely on one XCD? ----
  unsigned xcc;
  asm volatile("s_getreg_b32 %0, hwreg(HW_REG_XCC_ID)" : "=s"(xcc));
  if (tid == 0)
    __hip_atomic_store(&dir[w], (int)xcc + 1,
                       __ATOMIC_RELAXED, __HIP_MEMORY_SCOPE_AGENT);
  if (wv == 0) {
    int v = 0, spin = 0;
    for (;;) {
      v = __hip_atomic_load(&dir[bg + 8 * lane],
                            __ATOMIC_RELAXED, __HIP_MEMORY_SCOPE_AGENT);
      if (__ballot(v != 0) == ~0ull) break;
      if (++spin > (1 << 20)) break;   // all 512 WGs are co-resident; ~never
    }
    const int f0 = __shfl(v, 0);
    if (tid == 0)
      s_fast = (v != 0 && __ballot(v == f0) == ~0ull) ? 1 : 0;
  }
  __syncthreads();
  const bool fast = (s_fast != 0);

  for (int t = 0; t < 512; ++t) {
    // Prefetch x-contribution (overlaps the poll).
    unsigned long long zx8;
    if (t < 256) {
      // Encoder Zx rows: agent/sc1 (cache-bypass) -- required in slow mode,
      // harmless in fast mode (rows never alias the overlay).
      const size_t xrow = (size_t)(t * 64 + rglob);
      zx8 = __hip_atomic_load((const unsigned long long*)(Zx + xrow * 4096 + Q * 16 + gu * 4),
                              __ATOMIC_RELAXED, __HIP_MEMORY_SCOPE_AGENT);
    } else {
      // Decoder table rows 16384+tok: never overlaid -> normal load.
      const size_t xrow = (size_t)(16384 + tok_tgt[rglob * 256 + (t - 256)]);
      zx8 = *(const unsigned long long*)(Zx + xrow * 4096 + Q * 16 + gu * 4);
    }

    // ---- Flat per-chain barrier: wait until all 64 producers published. ----
    if (t > 0) {
      if (wv == 0) {
        int spin = 0;
        for (;;) {
          int v;
          if (fast) v = load_sc0(&slot_bg[lane * 32]);          // L2-local
          else      v = __hip_atomic_load(&slot_bg[lane * 32],
                                          __ATOMIC_RELAXED, __HIP_MEMORY_SCOPE_AGENT);
          if (__ballot(v >= t) == ~0ull) break;
          if (++spin > (1 << 18)) break;   // watchdog: garbage beats hang
        }
      }
      COMPILER_FENCE();
      __syncthreads();
    }

    // z_tile = h[16 rows][1024] @ Wh_slice[1024][16]; h via plain 16B loads
    // from the producer-major slab. fast: L1/L2-local (write-once or
    // rotation >> L1 capacity -> no staleness). slow: fills from MALL.
    f32x4 acc0 = {0.f, 0.f, 0.f, 0.f};
    f32x4 acc1 = {0.f, 0.f, 0.f, 0.f};
    f32x4 acc2 = {0.f, 0.f, 0.f, 0.f};
    f32x4 acc3 = {0.f, 0.f, 0.f, 0.f};
    if (t > 0) {
      const unsigned short* hb = chain_slab(Zx, hbuf1, chainD, t, bg);
      const unsigned short* ap = hb + (q >> 1) * 256 + m15 * 16 + (q & 1) * 8;
      short8 a[32];
#pragma unroll
      for (int kt = 0; kt < 32; ++kt)
        a[kt] = *(const short8*)(ap + kt * 512);
#pragma unroll
      for (int kt = 0; kt < 8; ++kt) {
        acc0 = MFMA16(a[kt],      Breg[kt],      acc0);
        acc1 = MFMA16(a[kt + 8],  Breg[kt + 8],  acc1);
        acc2 = MFMA16(a[kt + 16], Breg[kt + 16], acc2);
        acc3 = MFMA16(a[kt + 24], Breg[kt + 24], acc3);
      }
    }
    // Transpose through wave-private LDS: C-layout -> (row, unit) lanes.
#pragma unroll
    for (int i = 0; i < 4; ++i)
      zt_w[(q * 4 + i) * 17 + m15] = (acc0[i] + acc1[i]) + (acc2[i] + acc3[i]);
    __builtin_amdgcn_s_waitcnt(0xC07F);   // lgkmcnt(0)
    const float* zr = zt_w + gr * 17 + gu * 4;
    float z0 = zr[0], z1 = zr[1], z2 = zr[2], z3 = zr[3];

    z0 += bf2f((unsigned short)(zx8 >> 0))  + bias0;
    z1 += bf2f((unsigned short)(zx8 >> 16)) + bias1;
    z2 += bf2f((unsigned short)(zx8 >> 32)) + bias2;
    z3 += bf2f((unsigned short)(zx8 >> 48)) + bias3;

    const float ig = sigf(z0);
    const float jg = tanhf_fast(z1);
    const float fg = sigf(z2);
    const float og = sigf(z3);
    cst = fg * cst + ig * jg;
    const float hv = og * tanhf_fast(cst);
    const unsigned short hb16 = f2bf(hv);

    // Producer-major store: wave wv's 4 units for row gr -> 8B at block
    // ug*512B + gr*32B + wv*8B (sole writer of its lines).
    const unsigned int partner = (unsigned int)(unsigned short)__shfl_down((int)hb16, 1);
    const unsigned int hpack = (unsigned int)hb16 | (partner << 16);
    const unsigned int hpack2 = (unsigned int)__shfl_down((int)hpack, 2);
    if (gu == 0) {
      unsigned short* cb = chain_slab(Zx, hbuf1, chainD, t + 1, bg);
      unsigned long long* cq = (unsigned long long*)cb + ug * 64 + gr * 4 + wv;
      const unsigned long long hq =
          (unsigned long long)hpack | ((unsigned long long)hpack2 << 32);
      if (fast) *(volatile unsigned long long*)cq = hq;   // write-through to L2
      else __hip_atomic_store(cq, hq,
                              __ATOMIC_RELAXED, __HIP_MEMORY_SCOPE_AGENT);
    }

    // Drain own stores (fast: to L2; slow: to LLC), join waves, publish.
    COMPILER_FENCE();
    WAIT_VM0();
    COMPILER_FENCE();
    __syncthreads();
    if (tid == 0) {
      if (fast) *(volatile int*)&slot_bg[ug * 32] = t + 1;
      else __hip_atomic_store(&slot_bg[ug * 32], t + 1,
                              __ATOMIC_RELAXED, __HIP_MEMORY_SCOPE_AGENT);
    }
  }
}

// ---------------------------------------------------------------- k4
// Reads decoder h from chainD (producer-major): buffer td = blockIdx.x covers
// batch rows 0..63 (chain c = wv, local row r = m).
__global__ __launch_bounds__(256, 1)
void k4_proj(const unsigned short* __restrict__ hs,   // = chainD
             const unsigned short* __restrict__ WT,   // WprojT [64][1024]
             const float* __restrict__ b_proj,
             float* __restrict__ out)
{
  __shared__ __align__(16) unsigned short Wl[64 * 264];
  __shared__ float zb[4 * 16 * 68];
  const int tid = threadIdx.x;
  const int wv = tid >> 6, lane = tid & 63;
  const int q = lane >> 4, m = lane & 15;
  const int row0 = blockIdx.x * 64 + wv * 16;
  f32x4 acc[4];
#pragma unroll
  for (int nt = 0; nt < 4; ++nt) acc[nt] = (f32x4){0.f, 0.f, 0.f, 0.f};

  // Producer-major A addressing: unit u = kp*256 + kt*32 + q*8 + j ->
  // block pg = kp*16 + 2kt + (q>>1), short offset pg*256 + m*16 + (q&1)*8.
  const unsigned short* abase = hs + (size_t)blockIdx.x * 65536 + wv * 16384
                                + (q >> 1) * 256 + m * 16 + (q & 1) * 8;
  for (int kp = 0; kp < 4; ++kp) {
    __syncthreads();
    for (int i = tid; i < 64 * 32; i += 256) {
      const int n = i >> 5, kc = i & 31;
      *(short8*)(&Wl[n * 264 + kc * 8]) =
          *(const short8*)(WT + (size_t)n * 1024 + kp * 256 + kc * 8);
    }
    __syncthreads();
#pragma unroll 2
    for (int kt = 0; kt < 8; ++kt) {
      const short8 af = *(const short8*)(abase + kp * 4096 + kt * 512);
#pragma unroll
      for (int nt = 0; nt < 4; ++nt) {
        const short8 bfr = *(const short8*)(&Wl[(nt * 16 + m) * 264 + kt * 32 + q * 8]);
        acc[nt] = MFMA16(af, bfr, acc[nt]);
      }
    }
  }
  float* z = &zb[wv * (16 * 68)];
#pragma unroll
  for (int nt = 0; nt < 4; ++nt)
#pragma unroll
    for (int i = 0; i < 4; ++i)
      z[(q * 4 + i) * 68 + nt * 16 + m] = acc[nt][i];
  __syncthreads();
  const int r = lane >> 2, s = lane & 3;
  const float* zrow = z + r * 68 + s * 16;
  float v[16];
  float mx = -1e30f;
#pragma unroll
  for (int j = 0; j < 16; ++j) {
    v[j] = zrow[j] + b_proj[s * 16 + j];
    mx = fmaxf(mx, v[j]);
  }
  mx = fmaxf(mx, __shfl_xor(mx, 1));
  mx = fmaxf(mx, __shfl_xor(mx, 2));
  float sum = 0.f;
#pragma unroll
  for (int j = 0; j < 16; ++j) { v[j] = __expf(v[j] - mx); sum += v[j]; }
  sum += __shfl_xor(sum, 1);
  sum += __shfl_xor(sum, 2);
  const float inv = 1.0f / sum;
  const int nrow = row0 + r;
  const int b = nrow & 63, t = nrow >> 6;
  float* op = out + ((size_t)b * 256 + t) * 64 + s * 16;
#pragma unroll
  for (int x = 0; x < 4; ++x) {
    const float4v o4 = { v[4 * x] * inv, v[4 * x + 1] * inv,
                         v[4 * x + 2] * inv, v[4 * x + 3] * inv };
    *(float4v*)(op + 4 * x) = o4;
  }
}

// ---------------------------------------------------------------- launch
extern "C" void kernel_launch(void* const* d_in, const int* in_sizes, int n_in,
                              void* d_out, int out_size, void* d_ws, size_t ws_size,
                              hipStream_t stream)
{
  const int*   tok_src = (const int*)d_in[0];
  const int*   tok_tgt = (const int*)d_in[1];
  const float* emb_src = (const float*)d_in[2];
  const float* emb_tgt = (const float*)d_in[3];
  const float* W_lstm  = (const float*)d_in[4];
  const float* b_lstm  = (const float*)d_in[5];
  const float* W_proj  = (const float*)d_in[6];
  const float* b_proj  = (const float*)d_in[7];
  float* out = (float*)d_out;

  char* ws = (char*)d_ws;
  size_t off = 0;
  const size_t slot_bytes = (size_t)4 * 64 * 128;      // 128B line per (bg,ug)
  const size_t dir_bytes  = 512 * 4;                   // XCC_ID directory
  int* slot             = (int*)(ws + off);            off += slot_bytes;
  int* dir              = (int*)(ws + off);            off += dir_bytes;
  unsigned short* A     = (unsigned short*)(ws + off); off += (size_t)16512 * 512 * 2;
  unsigned short* WT    = (unsigned short*)(ws + off); off += (size_t)4096 * 1536 * 2;
  unsigned short* WPT   = (unsigned short*)(ws + off); off += (size_t)64 * 1024 * 2;
  unsigned short* Zx    = (unsigned short*)(ws + off); off += (size_t)16512 * 4096 * 2;
  unsigned short* hbuf1 = (unsigned short*)(ws + off); off += (size_t)64 * 1024 * 2;
  unsigned short* chainD= (unsigned short*)(ws + off); off += (size_t)256 * 64 * 1024 * 2;
  if (ws_size < off) return;  // insufficient workspace -> loud correctness failure

  hipMemsetAsync(slot, 0, slot_bytes + dir_bytes, stream);
  hipLaunchKernelGGL(k1a_gather, dim3(16512), dim3(128), 0, stream, tok_src, emb_src, emb_tgt, A);
  hipLaunchKernelGGL(k1w_perm,   dim3(3072),  dim3(256), 0, stream, W_lstm, WT);
  hipLaunchKernelGGL(k1p_perm,   dim3(32),    dim3(256), 0, stream, W_proj, WPT);
  hipLaunchKernelGGL(k2_gemm,    dim3(32, 129), dim3(256), 0, stream, A, WT, Zx);
  hipLaunchKernelGGL(k3_rnn,     dim3(512),   dim3(256), 0, stream, Zx, WT, b_lstm, tok_tgt, hbuf1, chainD, slot, dir);
  hipLaunchKernelGGL(k4_proj,    dim3(256),   dim3(256), 0, stream, chainD, WPT, b_proj, out);
}

// Round 6
// 2972.698 us; speedup vs baseline: 1.1723x; 1.1723x over previous
//
#include <hip/hip_runtime.h>

// Seq2seq LSTM (B=64, T=256, E=512, H=1024, V_TGT=64) on gfx950.
//   k1a: gather+convert A_bf16[16512][512]
//   k1w: W_lstm fp32 [1536][4096] -> WpermT bf16 [4096][1536] (col-permuted)
//   k1p: W_proj -> WprojT bf16 [64][1024]
//   k2 : Zx bf16 [16512][4096] = A @ Wx
//   k3 : persistent 256-WG recurrence, 4 independent per-bg chains.
//        Round-12: REGISTER-FIT restructure. r6-r11 invariants: every sync
//        design = 5.3-5.7us/step AND VGPR_Count=100 while the loop nominally
//        needs 256+ VGPRs (Breg[32]+a[32]) -> the compiler rematerializes W
//        from memory every step and dribbles h-loads in register-limited
//        batches (several exposed latencies/step), plus 64KB working set
//        thrashing the 32KB L1. Fix: WG = 512 threads (8 waves); each
//        unit-quad's K=1024 is SPLIT across a wave pair (kh = wv&1), so each
//        wave holds Breg[16] (64 VGPR) + a[16] (64 VGPR) + accs ~= 185 VGPR
//        at launch_bounds(512,2) -> W stays resident, h-loads issue as ONE
//        batch. Wave pair combines partials in LDS (ztile); even waves run
//        gates/store/publish. Protocol/slabs/overlay = r10 (agent scope,
//        128B slots, producer-major slabs, publish-after-drain).
//        Lessons kept: r8 = never interleave polls with in-flight loads;
//        r9 = phase-interleaved chains serialize; r11 = transport scope is
//        not the binding constraint.
//   k4 : projection + softmax -> d_out fp32 [64][256][64]

typedef __attribute__((ext_vector_type(8))) short short8;        // bf16 frag
typedef __attribute__((ext_vector_type(4))) float f32x4;         // MFMA acc
typedef __attribute__((ext_vector_type(4))) float float4v;
typedef __attribute__((ext_vector_type(4))) unsigned short ushort4v;

#define MFMA16(A, B, C) __builtin_amdgcn_mfma_f32_16x16x32_bf16((A), (B), (C), 0, 0, 0)
#define WAIT_VM0() __builtin_amdgcn_s_waitcnt(0x0F70)   // vmcnt(0), ignore exp/lgkm
#define COMPILER_FENCE() asm volatile("" ::: "memory")

__device__ __forceinline__ unsigned short f2bf(float f) {
  union { float f; unsigned u; } v; v.f = f;
  unsigned r = (v.u + 0x7fffu + ((v.u >> 16) & 1u)) >> 16;   // RNE, no NaN in data
  return (unsigned short)r;
}
__device__ __forceinline__ float bf2f(unsigned short h) {
  union { unsigned u; float f; } v; v.u = ((unsigned)h) << 16;
  return v.f;
}
__device__ __forceinline__ float sigf(float x) { return 1.0f / (1.0f + __expf(-x)); }
__device__ __forceinline__ float tanhf_fast(float x) { return 1.0f - 2.0f / (1.0f + __expf(2.0f * x)); }

// Chain slab for chain c at step t (h consumed at step t), PRODUCER-MAJOR:
// 64 blocks x 512B; block ug = [16 rows][16 units] (row-major inside block).
//   t==1      : hbuf1 + c*16384 shorts
//   2..256    : overlay dead Zx rows (t-2)*64 + 16c..+15 (consumed by chain c
//               itself at step t-2; publish-after-drain makes this safe)
//   257..512  : chainD + (t-257)*65536 + c*16384 (k4's input)
__device__ __forceinline__ unsigned short*
chain_slab(unsigned short* Zx, unsigned short* hbuf1, unsigned short* chainD,
           int t, int c)
{
  if (t == 1)  return hbuf1 + c * 16384;
  if (t < 257) return Zx + (size_t)(t - 2) * 262144 + c * 65536;
  return chainD + (size_t)(t - 257) * 65536 + c * 16384;
}

// ---------------------------------------------------------------- k1a
__global__ __launch_bounds__(128)
void k1a_gather(const int* __restrict__ tok_src,
                const float* __restrict__ emb_src,
                const float* __restrict__ emb_tgt,
                unsigned short* __restrict__ A)
{
  const int n = blockIdx.x;     // 0..16511
  const int i = threadIdx.x;    // 0..127, each does 4 elements
  float4v v = {0.f, 0.f, 0.f, 0.f};
  if (n < 16384) {
    const int b = n & 63, t = n >> 6;                 // row n = t*64 + b
    const int tk = tok_src[b * 256 + t];              // input_source[b][t]
    v = *(const float4v*)(emb_src + (size_t)tk * 512 + i * 4);
  } else if (n < 16448) {
    v = *(const float4v*)(emb_tgt + (size_t)(n - 16384) * 512 + i * 4);
  }
  ushort4v o;
  o.x = f2bf(v.x); o.y = f2bf(v.y); o.z = f2bf(v.z); o.w = f2bf(v.w);
  *(ushort4v*)(A + (size_t)n * 512 + i * 4) = o;
}

// ---------------------------------------------------------------- k1w
__global__ __launch_bounds__(256)
void k1w_perm(const float* __restrict__ W, unsigned short* __restrict__ WT)
{
  const int id = blockIdx.x * 256 + threadIdx.x;  // < 786432 = 4096 * 192
  const int n  = id & 4095;                        // permuted col
  const int k0 = (id >> 12) * 8;                   // 0..1528
  const int g = n & 3, u = (n >> 2) & 3, wq = n >> 4;
  const int oc = g * 1024 + 4 * wq + u;
  short8 o;
#pragma unroll
  for (int j = 0; j < 8; ++j)
    o[j] = (short)f2bf(W[(size_t)(k0 + j) * 4096 + oc]);
  *(short8*)(WT + (size_t)n * 1536 + k0) = o;
}

// ---------------------------------------------------------------- k1p
__global__ __launch_bounds__(256)
void k1p_perm(const float* __restrict__ W, unsigned short* __restrict__ WT)
{
  const int id = blockIdx.x * 256 + threadIdx.x;  // < 8192 = 64 * 128
  const int n  = id & 63;
  const int k0 = (id >> 6) * 8;
  short8 o;
#pragma unroll
  for (int j = 0; j < 8; ++j)
    o[j] = (short)f2bf(W[(size_t)(k0 + j) * 64 + n]);
  *(short8*)(WT + (size_t)n * 1024 + k0) = o;
}

// ---------------------------------------------------------------- k2
__global__ __launch_bounds__(256, 1)
void k2_gemm(const unsigned short* __restrict__ A,
             const unsigned short* __restrict__ BT,
             unsigned short* __restrict__ C)
{
  __shared__ __align__(16) unsigned short As[128 * 40];
  __shared__ __align__(16) unsigned short Bs[128 * 40];
  const int tid = threadIdx.x;
  const int n0 = blockIdx.x * 128;   // 32 blocks
  const int m0 = blockIdx.y * 128;   // 129 blocks
  const int wv = tid >> 6, lane = tid & 63;
  const int wr = wv & 1, wc = wv >> 1;
  const int q = lane >> 4, l15 = lane & 15;
  f32x4 acc[4][4];
#pragma unroll
  for (int a = 0; a < 4; ++a)
#pragma unroll
    for (int b = 0; b < 4; ++b)
      acc[a][b] = (f32x4){0.f, 0.f, 0.f, 0.f};

  for (int kt = 0; kt < 16; ++kt) {   // K = 512, BK = 32
    __syncthreads();
#pragma unroll
    for (int s = 0; s < 2; ++s) {
      const int ci = tid + s * 256;
      const int row = ci >> 2, kc = ci & 3;
      *(short8*)(&As[row * 40 + kc * 8]) =
          *(const short8*)(A + (size_t)(m0 + row) * 512 + kt * 32 + kc * 8);
      *(short8*)(&Bs[row * 40 + kc * 8]) =
          *(const short8*)(BT + (size_t)(n0 + row) * 1536 + kt * 32 + kc * 8);
    }
    __syncthreads();
    short8 af[4], bf[4];
#pragma unroll
    for (int i = 0; i < 4; ++i) {
      af[i] = *(const short8*)(&As[(wr * 64 + i * 16 + l15) * 40 + q * 8]);
      bf[i] = *(const short8*)(&Bs[(wc * 64 + i * 16 + l15) * 40 + q * 8]);
    }
#pragma unroll
    for (int mi = 0; mi < 4; ++mi)
#pragma unroll
      for (int ni = 0; ni < 4; ++ni)
        acc[mi][ni] = MFMA16(af[mi], bf[ni], acc[mi][ni]);
  }
#pragma unroll
  for (int mi = 0; mi < 4; ++mi)
#pragma unroll
    for (int ni = 0; ni < 4; ++ni)
#pragma unroll
      for (int i = 0; i < 4; ++i) {
        const int row = m0 + wr * 64 + mi * 16 + q * 4 + i;
        const int col = n0 + wc * 64 + ni * 16 + l15;
        C[(size_t)row * 4096 + col] = f2bf(acc[mi][ni][i]);
      }
}

// ---------------------------------------------------------------- k3
// 256 WGs x 512 threads (8 waves), 512 steps, 4 independent per-bg chains.
// WG w: bg = (w>>1)&3, ug = ((w>>3)<<1)|(w&1) in 0..63. Wave wv: quad
// qd = wv>>1 (Q = 4*ug+qd), K-half kh = wv&1 (h units kh*512..+511).
// Each wave: Breg[16] + a[16] (fits in registers). Wave pair combines
// partial z in LDS; even (kh==0) waves run gates/store. Slot[bg][ug] at
// 128B stride = completed step count (sole writer per line).
__global__ __launch_bounds__(512, 2)
void k3_rnn(unsigned short* __restrict__ Zx,
            const unsigned short* __restrict__ WT,
            const float* __restrict__ b_lstm,
            const int* __restrict__ tok_tgt,
            unsigned short* __restrict__ hbuf1,    // C_1 (128 KB)
            unsigned short* __restrict__ chainD,   // C_257..C_512 (32 MB)
            int* __restrict__ slot)                // [4][64] counters, 128B stride
{
  __shared__ float ztile[8 * 272];                 // per-wave 16x16 (+1 pad)
  const int w = blockIdx.x;
  const int tid = threadIdx.x;
  const int wv = tid >> 6, lane = tid & 63;
  const int bg = (w >> 1) & 3;                 // batch group (XCD-affine)
  const int ug = ((w >> 3) << 1) | (w & 1);    // unit group 0..63
  const int qd = wv >> 1;                      // quad within WG (0..3)
  const int kh = wv & 1;                       // K-half (0..1)
  const int Q  = 4 * ug + qd;                  // unit-quad (0..255)
  int* const slot_bg = slot + bg * 2048;       // 64 slots, 32-int stride

  // Gate-phase lane mapping (even waves): 64 lanes = 16 rows x 4 units.
  const int gr = lane >> 2, gu = lane & 3;
  const int rglob = bg * 16 + gr;
  const float bias0 = b_lstm[4 * Q + gu];                  // i
  const float bias1 = b_lstm[1024 + 4 * Q + gu];           // j
  const float bias2 = b_lstm[2048 + 4 * Q + gu] + 1.0f;    // f + forget_bias
  const float bias3 = b_lstm[3072 + 4 * Q + gu];           // o
  float cst = 0.f;
  // MFMA-phase lane mapping.
  const int q = lane >> 4, m15 = lane & 15;
  float* const zt_w = &ztile[wv * 272];
  float* const zt_lo = &ztile[(wv & ~1) * 272];
  float* const zt_hi = zt_lo + 272;

  // Wave's W_h B-frags: WT row Q*16+m15, k = 512 + kh*512 + kt*32 + q*8.
  // 16 frags = 64 VGPRs -> stays register-resident at this pressure.
  short8 Breg[16];
  {
    const unsigned short* wsrc =
        WT + (size_t)(Q * 16 + m15) * 1536 + 512 + kh * 512 + q * 8;
#pragma unroll
    for (int kt = 0; kt < 16; ++kt)
      Breg[kt] = *(const short8*)(wsrc + kt * 32);
  }

  for (int t = 0; t < 512; ++t) {
    // Even-wave zx prefetch (overlaps the poll).
    unsigned long long zx8 = 0;
    if (kh == 0) {
      if (t < 256) {
        // Encoder Zx rows: agent-scope (cache-bypass) -- overlay safety.
        const size_t xrow = (size_t)(t * 64 + rglob);
        zx8 = __hip_atomic_load((const unsigned long long*)(Zx + xrow * 4096 + Q * 16 + gu * 4),
                                __ATOMIC_RELAXED, __HIP_MEMORY_SCOPE_AGENT);
      } else {
        // Decoder table rows 16384+tok: never overlaid -> normal load.
        const size_t xrow = (size_t)(16384 + tok_tgt[rglob * 256 + (t - 256)]);
        zx8 = *(const unsigned long long*)(Zx + xrow * 4096 + Q * 16 + gu * 4);
      }
    }

    // ---- Flat per-bg barrier: wait until all 64 producers published C_t. ----
    if (t > 0) {
      if (wv == 0) {
        int spin = 0;
        for (;;) {
          const int v = __hip_atomic_load(&slot_bg[lane * 32],
                                          __ATOMIC_RELAXED, __HIP_MEMORY_SCOPE_AGENT);
          if (__ballot(v >= t) == ~0ull) break;
          if (++spin > (1 << 18)) break;   // watchdog: garbage beats hang
        }
      }
      COMPILER_FENCE();
      __syncthreads();
    }

    // Partial z: h[16 rows][512 (this K-half)] @ Wh_half[512][16 gate-cols].
    // 16 plain 16B loads issued as ONE batch (fits registers), then 16 MFMAs.
    f32x4 acc0 = {0.f, 0.f, 0.f, 0.f};
    f32x4 acc1 = {0.f, 0.f, 0.f, 0.f};
    f32x4 acc2 = {0.f, 0.f, 0.f, 0.f};
    f32x4 acc3 = {0.f, 0.f, 0.f, 0.f};
    if (t > 0) {
      const unsigned short* hb = chain_slab(Zx, hbuf1, chainD, t, bg);
      const unsigned short* ap =
          hb + kh * 8192 + (q >> 1) * 256 + m15 * 16 + (q & 1) * 8;
      short8 a[16];
#pragma unroll
      for (int kt = 0; kt < 16; ++kt)
        a[kt] = *(const short8*)(ap + kt * 512);
#pragma unroll
      for (int j = 0; j < 4; ++j) {
        acc0 = MFMA16(a[j],      Breg[j],      acc0);
        acc1 = MFMA16(a[j + 4],  Breg[j + 4],  acc1);
        acc2 = MFMA16(a[j + 8],  Breg[j + 8],  acc2);
        acc3 = MFMA16(a[j + 12], Breg[j + 12], acc3);
      }
    }
    // Partial write: C-layout -> LDS (cross-wave combine needs syncthreads).
#pragma unroll
    for (int i = 0; i < 4; ++i)
      zt_w[(q * 4 + i) * 17 + m15] = (acc0[i] + acc1[i]) + (acc2[i] + acc3[i]);
    __syncthreads();

    if (kh == 0) {
      const float* zr0 = zt_lo + gr * 17 + gu * 4;
      const float* zr1 = zt_hi + gr * 17 + gu * 4;
      float z0 = zr0[0] + zr1[0];
      float z1 = zr0[1] + zr1[1];
      float z2 = zr0[2] + zr1[2];
      float z3 = zr0[3] + zr1[3];

      z0 += bf2f((unsigned short)(zx8 >> 0))  + bias0;
      z1 += bf2f((unsigned short)(zx8 >> 16)) + bias1;
      z2 += bf2f((unsigned short)(zx8 >> 32)) + bias2;
      z3 += bf2f((unsigned short)(zx8 >> 48)) + bias3;

      const float ig = sigf(z0);
      const float jg = tanhf_fast(z1);
      const float fg = sigf(z2);
      const float og = sigf(z3);
      cst = fg * cst + ig * jg;
      const float hv = og * tanhf_fast(cst);
      const unsigned short hb16 = f2bf(hv);

      // Producer-major store: quad qd's 4 units for row gr -> 8B at block
      // ug*512B + gr*32B + qd*8B (sole writer of its lines).
      const unsigned int partner = (unsigned int)(unsigned short)__shfl_down((int)hb16, 1);
      const unsigned int hpack = (unsigned int)hb16 | (partner << 16);
      const unsigned int hpack2 = (unsigned int)__shfl_down((int)hpack, 2);
      if (gu == 0) {
        unsigned short* cb = chain_slab(Zx, hbuf1, chainD, t + 1, bg);
        unsigned long long* cq = (unsigned long long*)cb + ug * 64 + gr * 4 + qd;
        const unsigned long long hq =
            (unsigned long long)hpack | ((unsigned long long)hpack2 << 32);
        __hip_atomic_store(cq, hq,
                           __ATOMIC_RELAXED, __HIP_MEMORY_SCOPE_AGENT);
      }
    }

    // Drain own stores, join waves, publish step count.
    COMPILER_FENCE();
    WAIT_VM0();
    COMPILER_FENCE();
    __syncthreads();
    if (tid == 0)
      __hip_atomic_store(&slot_bg[ug * 32], t + 1,
                         __ATOMIC_RELAXED, __HIP_MEMORY_SCOPE_AGENT);
  }
}

// ---------------------------------------------------------------- k4
// Reads decoder h from chainD (producer-major): buffer td = blockIdx.x covers
// batch rows 0..63 (chain c = wv, local row r = m).
__global__ __launch_bounds__(256, 1)
void k4_proj(const unsigned short* __restrict__ hs,   // = chainD
             const unsigned short* __restrict__ WT,   // WprojT [64][1024]
             const float* __restrict__ b_proj,
             float* __restrict__ out)
{
  __shared__ __align__(16) unsigned short Wl[64 * 264];
  __shared__ float zb[4 * 16 * 68];
  const int tid = threadIdx.x;
  const int wv = tid >> 6, lane = tid & 63;
  const int q = lane >> 4, m = lane & 15;
  const int row0 = blockIdx.x * 64 + wv * 16;
  f32x4 acc[4];
#pragma unroll
  for (int nt = 0; nt < 4; ++nt) acc[nt] = (f32x4){0.f, 0.f, 0.f, 0.f};

  // Producer-major A addressing: unit u = kp*256 + kt*32 + q*8 + j ->
  // block pg = kp*16 + 2kt + (q>>1), short offset pg*256 + m*16 + (q&1)*8.
  const unsigned short* abase = hs + (size_t)blockIdx.x * 65536 + wv * 16384
                                + (q >> 1) * 256 + m * 16 + (q & 1) * 8;
  for (int kp = 0; kp < 4; ++kp) {
    __syncthreads();
    for (int i = tid; i < 64 * 32; i += 256) {
      const int n = i >> 5, kc = i & 31;
      *(short8*)(&Wl[n * 264 + kc * 8]) =
          *(const short8*)(WT + (size_t)n * 1024 + kp * 256 + kc * 8);
    }
    __syncthreads();
#pragma unroll 2
    for (int kt = 0; kt < 8; ++kt) {
      const short8 af = *(const short8*)(abase + kp * 4096 + kt * 512);
#pragma unroll
      for (int nt = 0; nt < 4; ++nt) {
        const short8 bfr = *(const short8*)(&Wl[(nt * 16 + m) * 264 + kt * 32 + q * 8]);
        acc[nt] = MFMA16(af, bfr, acc[nt]);
      }
    }
  }
  float* z = &zb[wv * (16 * 68)];
#pragma unroll
  for (int nt = 0; nt < 4; ++nt)
#pragma unroll
    for (int i = 0; i < 4; ++i)
      z[(q * 4 + i) * 68 + nt * 16 + m] = acc[nt][i];
  __syncthreads();
  const int r = lane >> 2, s = lane & 3;
  const float* zrow = z + r * 68 + s * 16;
  float v[16];
  float mx = -1e30f;
#pragma unroll
  for (int j = 0; j < 16; ++j) {
    v[j] = zrow[j] + b_proj[s * 16 + j];
    mx = fmaxf(mx, v[j]);
  }
  mx = fmaxf(mx, __shfl_xor(mx, 1));
  mx = fmaxf(mx, __shfl_xor(mx, 2));
  float sum = 0.f;
#pragma unroll
  for (int j = 0; j < 16; ++j) { v[j] = __expf(v[j] - mx); sum += v[j]; }
  sum += __shfl_xor(sum, 1);
  sum += __shfl_xor(sum, 2);
  const float inv = 1.0f / sum;
  const int nrow = row0 + r;
  const int b = nrow & 63, t = nrow >> 6;
  float* op = out + ((size_t)b * 256 + t) * 64 + s * 16;
#pragma unroll
  for (int x = 0; x < 4; ++x) {
    const float4v o4 = { v[4 * x] * inv, v[4 * x + 1] * inv,
                         v[4 * x + 2] * inv, v[4 * x + 3] * inv };
    *(float4v*)(op + 4 * x) = o4;
  }
}

// ---------------------------------------------------------------- launch
extern "C" void kernel_launch(void* const* d_in, const int* in_sizes, int n_in,
                              void* d_out, int out_size, void* d_ws, size_t ws_size,
                              hipStream_t stream)
{
  const int*   tok_src = (const int*)d_in[0];
  const int*   tok_tgt = (const int*)d_in[1];
  const float* emb_src = (const float*)d_in[2];
  const float* emb_tgt = (const float*)d_in[3];
  const float* W_lstm  = (const float*)d_in[4];
  const float* b_lstm  = (const float*)d_in[5];
  const float* W_proj  = (const float*)d_in[6];
  const float* b_proj  = (const float*)d_in[7];
  float* out = (float*)d_out;

  char* ws = (char*)d_ws;
  size_t off = 0;
  const size_t slot_bytes = (size_t)4 * 64 * 128;      // 128B line per (bg,ug)
  int* slot             = (int*)(ws + off);            off += slot_bytes;
  unsigned short* A     = (unsigned short*)(ws + off); off += (size_t)16512 * 512 * 2;
  unsigned short* WT    = (unsigned short*)(ws + off); off += (size_t)4096 * 1536 * 2;
  unsigned short* WPT   = (unsigned short*)(ws + off); off += (size_t)64 * 1024 * 2;
  unsigned short* Zx    = (unsigned short*)(ws + off); off += (size_t)16512 * 4096 * 2;
  unsigned short* hbuf1 = (unsigned short*)(ws + off); off += (size_t)64 * 1024 * 2;
  unsigned short* chainD= (unsigned short*)(ws + off); off += (size_t)256 * 64 * 1024 * 2;
  if (ws_size < off) return;  // insufficient workspace -> loud correctness failure

  hipMemsetAsync(slot, 0, slot_bytes, stream);
  hipLaunchKernelGGL(k1a_gather, dim3(16512), dim3(128), 0, stream, tok_src, emb_src, emb_tgt, A);
  hipLaunchKernelGGL(k1w_perm,   dim3(3072),  dim3(256), 0, stream, W_lstm, WT);
  hipLaunchKernelGGL(k1p_perm,   dim3(32),    dim3(256), 0, stream, W_proj, WPT);
  hipLaunchKernelGGL(k2_gemm,    dim3(32, 129), dim3(256), 0, stream, A, WT, Zx);
  hipLaunchKernelGGL(k3_rnn,     dim3(256),   dim3(512), 0, stream, Zx, WT, b_lstm, tok_tgt, hbuf1, chainD, slot);
  hipLaunchKernelGGL(k4_proj,    dim3(256),   dim3(256), 0, stream, chainD, WPT, b_proj, out);
}

// Round 7
// 1745.985 us; speedup vs baseline: 1.9960x; 1.7026x over previous
//
#include <hip/hip_runtime.h>

// Seq2seq LSTM (B=64, T=256, E=512, H=1024, V_TGT=64) on gfx950.
//   k1a: gather+convert A_bf16[16512][512]
//   k1w: W_lstm fp32 [1536][4096] -> WpermT bf16 [4096][1536] (col-permuted)
//   k1p: W_proj -> WprojT bf16 [64][1024]
//   k2 : Zx bf16 [16512][4096] = A @ Wx
//   k3 : persistent 256-WG recurrence, 4 independent per-bg chains (r10
//        protocol: 128B-stride slots, producer-major slabs, publish-after-
//        drain). Round-13: KILL THE DRIBBLE.
//        r6-r12 invariant: VGPR_Count stuck at 64-104 while the loop wants
//        256+ -> compiler rematerializes W every step and issues h-loads in
//        register-limited dribbles (~4-8 exposed L2/MALL round trips/step).
//        r9 proved it: phases with ZERO barrier wait still took 5.2us.
//        Fixes:
//        (a) h slab (32KB) staged to LDS via global_load_lds (async, no VGPR
//            round-trip, 8x1KB per wave, ONE vmcnt(0)) -> one exposed latency
//            per step. MFMA A-frags then come from ds_read_b128.
//        (b) Breg pinned with opaque asm INSIDE the t-loop (r10 pinned before
//            the loop -> loop-invariant SSA -> remat stayed legal; in-loop
//            redefinition makes remat impossible). 128 VGPR held.
//        Lessons kept: r8 = never interleave polls with in-flight loads;
//        r9 = phase-interleaved chains serialize; r11 = transport scope
//        secondary; r12 = K-split only treated the symptom.
//   k4 : projection + softmax -> d_out fp32 [64][256][64]

typedef __attribute__((ext_vector_type(8))) short short8;        // bf16 frag
typedef __attribute__((ext_vector_type(4))) float f32x4;         // MFMA acc
typedef __attribute__((ext_vector_type(4))) float float4v;
typedef __attribute__((ext_vector_type(4))) unsigned short ushort4v;

#define MFMA16(A, B, C) __builtin_amdgcn_mfma_f32_16x16x32_bf16((A), (B), (C), 0, 0, 0)
#define WAIT_VM0() __builtin_amdgcn_s_waitcnt(0x0F70)   // vmcnt(0), ignore exp/lgkm
#define COMPILER_FENCE() asm volatile("" ::: "memory")

__device__ __forceinline__ unsigned short f2bf(float f) {
  union { float f; unsigned u; } v; v.f = f;
  unsigned r = (v.u + 0x7fffu + ((v.u >> 16) & 1u)) >> 16;   // RNE, no NaN in data
  return (unsigned short)r;
}
__device__ __forceinline__ float bf2f(unsigned short h) {
  union { unsigned u; float f; } v; v.u = ((unsigned)h) << 16;
  return v.f;
}
__device__ __forceinline__ float sigf(float x) { return 1.0f / (1.0f + __expf(-x)); }
__device__ __forceinline__ float tanhf_fast(float x) { return 1.0f - 2.0f / (1.0f + __expf(2.0f * x)); }

// Chain slab for chain c at step t (h consumed at step t), PRODUCER-MAJOR:
// 64 blocks x 512B; block ug = [16 rows][16 units] (row-major inside block).
//   t==1      : hbuf1 + c*16384 shorts
//   2..256    : overlay dead Zx rows (t-2)*64 + 16c..+15 (consumed by chain c
//               itself at step t-2; publish-after-drain makes this safe)
//   257..512  : chainD + (t-257)*65536 + c*16384 (k4's input)
__device__ __forceinline__ unsigned short*
chain_slab(unsigned short* Zx, unsigned short* hbuf1, unsigned short* chainD,
           int t, int c)
{
  if (t == 1)  return hbuf1 + c * 16384;
  if (t < 257) return Zx + (size_t)(t - 2) * 262144 + c * 65536;
  return chainD + (size_t)(t - 257) * 65536 + c * 16384;
}

// ---------------------------------------------------------------- k1a
__global__ __launch_bounds__(128)
void k1a_gather(const int* __restrict__ tok_src,
                const float* __restrict__ emb_src,
                const float* __restrict__ emb_tgt,
                unsigned short* __restrict__ A)
{
  const int n = blockIdx.x;     // 0..16511
  const int i = threadIdx.x;    // 0..127, each does 4 elements
  float4v v = {0.f, 0.f, 0.f, 0.f};
  if (n < 16384) {
    const int b = n & 63, t = n >> 6;                 // row n = t*64 + b
    const int tk = tok_src[b * 256 + t];              // input_source[b][t]
    v = *(const float4v*)(emb_src + (size_t)tk * 512 + i * 4);
  } else if (n < 16448) {
    v = *(const float4v*)(emb_tgt + (size_t)(n - 16384) * 512 + i * 4);
  }
  ushort4v o;
  o.x = f2bf(v.x); o.y = f2bf(v.y); o.z = f2bf(v.z); o.w = f2bf(v.w);
  *(ushort4v*)(A + (size_t)n * 512 + i * 4) = o;
}

// ---------------------------------------------------------------- k1w
__global__ __launch_bounds__(256)
void k1w_perm(const float* __restrict__ W, unsigned short* __restrict__ WT)
{
  const int id = blockIdx.x * 256 + threadIdx.x;  // < 786432 = 4096 * 192
  const int n  = id & 4095;                        // permuted col
  const int k0 = (id >> 12) * 8;                   // 0..1528
  const int g = n & 3, u = (n >> 2) & 3, wq = n >> 4;
  const int oc = g * 1024 + 4 * wq + u;
  short8 o;
#pragma unroll
  for (int j = 0; j < 8; ++j)
    o[j] = (short)f2bf(W[(size_t)(k0 + j) * 4096 + oc]);
  *(short8*)(WT + (size_t)n * 1536 + k0) = o;
}

// ---------------------------------------------------------------- k1p
__global__ __launch_bounds__(256)
void k1p_perm(const float* __restrict__ W, unsigned short* __restrict__ WT)
{
  const int id = blockIdx.x * 256 + threadIdx.x;  // < 8192 = 64 * 128
  const int n  = id & 63;
  const int k0 = (id >> 6) * 8;
  short8 o;
#pragma unroll
  for (int j = 0; j < 8; ++j)
    o[j] = (short)f2bf(W[(size_t)(k0 + j) * 64 + n]);
  *(short8*)(WT + (size_t)n * 1024 + k0) = o;
}

// ---------------------------------------------------------------- k2
__global__ __launch_bounds__(256, 1)
void k2_gemm(const unsigned short* __restrict__ A,
             const unsigned short* __restrict__ BT,
             unsigned short* __restrict__ C)
{
  __shared__ __align__(16) unsigned short As[128 * 40];
  __shared__ __align__(16) unsigned short Bs[128 * 40];
  const int tid = threadIdx.x;
  const int n0 = blockIdx.x * 128;   // 32 blocks
  const int m0 = blockIdx.y * 128;   // 129 blocks
  const int wv = tid >> 6, lane = tid & 63;
  const int wr = wv & 1, wc = wv >> 1;
  const int q = lane >> 4, l15 = lane & 15;
  f32x4 acc[4][4];
#pragma unroll
  for (int a = 0; a < 4; ++a)
#pragma unroll
    for (int b = 0; b < 4; ++b)
      acc[a][b] = (f32x4){0.f, 0.f, 0.f, 0.f};

  for (int kt = 0; kt < 16; ++kt) {   // K = 512, BK = 32
    __syncthreads();
#pragma unroll
    for (int s = 0; s < 2; ++s) {
      const int ci = tid + s * 256;
      const int row = ci >> 2, kc = ci & 3;
      *(short8*)(&As[row * 40 + kc * 8]) =
          *(const short8*)(A + (size_t)(m0 + row) * 512 + kt * 32 + kc * 8);
      *(short8*)(&Bs[row * 40 + kc * 8]) =
          *(const short8*)(BT + (size_t)(n0 + row) * 1536 + kt * 32 + kc * 8);
    }
    __syncthreads();
    short8 af[4], bf[4];
#pragma unroll
    for (int i = 0; i < 4; ++i) {
      af[i] = *(const short8*)(&As[(wr * 64 + i * 16 + l15) * 40 + q * 8]);
      bf[i] = *(const short8*)(&Bs[(wc * 64 + i * 16 + l15) * 40 + q * 8]);
    }
#pragma unroll
    for (int mi = 0; mi < 4; ++mi)
#pragma unroll
      for (int ni = 0; ni < 4; ++ni)
        acc[mi][ni] = MFMA16(af[mi], bf[ni], acc[mi][ni]);
  }
#pragma unroll
  for (int mi = 0; mi < 4; ++mi)
#pragma unroll
    for (int ni = 0; ni < 4; ++ni)
#pragma unroll
      for (int i = 0; i < 4; ++i) {
        const int row = m0 + wr * 64 + mi * 16 + q * 4 + i;
        const int col = n0 + wc * 64 + ni * 16 + l15;
        C[(size_t)row * 4096 + col] = f2bf(acc[mi][ni][i]);
      }
}

// ---------------------------------------------------------------- k3
// 256 WGs x 256 threads, 512 steps, 4 independent per-bg chains.
// WG w: bg = (w>>1)&3, ug = ((w>>3)<<1)|(w&1) in 0..63. Wave wv -> unit-quad
// Q = 4*ug + wv. All 4 waves consume the same staged h slab from LDS.
// Slot[bg][ug] at 128B stride = completed step count (sole writer per line).
__global__ __launch_bounds__(256, 1)
void k3_rnn(unsigned short* __restrict__ Zx,
            const unsigned short* __restrict__ WT,
            const float* __restrict__ b_lstm,
            const int* __restrict__ tok_tgt,
            unsigned short* __restrict__ hbuf1,    // C_1 (128 KB)
            unsigned short* __restrict__ chainD,   // C_257..C_512 (32 MB)
            int* __restrict__ slot)                // [4][64] counters, 128B stride
{
  __shared__ __align__(16) unsigned short hstage[16384];   // 32 KB h slab
  __shared__ float ztile[4 * 272];                         // per-wave 16x16 (+1)
  const int w = blockIdx.x;
  const int tid = threadIdx.x;
  const int wv = tid >> 6, lane = tid & 63;
  const int bg = (w >> 1) & 3;                 // batch group (XCD-affine)
  const int ug = ((w >> 3) << 1) | (w & 1);    // unit group 0..63
  const int Q  = 4 * ug + wv;                  // this wave's unit-quad (0..255)
  int* const slot_bg = slot + bg * 2048;       // 64 slots, 32-int stride

  // Gate-phase lane mapping: 64 lanes = 16 rows x 4 units.
  const int gr = lane >> 2, gu = lane & 3;
  const int rglob = bg * 16 + gr;
  const float bias0 = b_lstm[4 * Q + gu];                  // i
  const float bias1 = b_lstm[1024 + 4 * Q + gu];           // j
  const float bias2 = b_lstm[2048 + 4 * Q + gu] + 1.0f;    // f + forget_bias
  const float bias3 = b_lstm[3072 + 4 * Q + gu];           // o
  float cst = 0.f;
  // MFMA-phase lane mapping.
  const int q = lane >> 4, m15 = lane & 15;
  float* const zt_w = &ztile[wv * 272];
  // LDS A-frag base for this lane (mirrors the producer-major slab layout).
  const unsigned short* const lfrag = hstage + (q >> 1) * 256 + m15 * 16 + (q & 1) * 8;

  // Wave's W_h B-frags: WT row Q*16+m15, k = 512 + kt*32 + q*8 (128 VGPRs).
  short8 Breg[32];
  {
    const unsigned short* wsrc = WT + (size_t)(Q * 16 + m15) * 1536 + 512 + q * 8;
#pragma unroll
    for (int kt = 0; kt < 32; ++kt)
      Breg[kt] = *(const short8*)(wsrc + kt * 32);
  }

  for (int t = 0; t < 512; ++t) {
    // PIN Breg: in-loop opaque redefinition -> rematerialization impossible,
    // the 128 VGPRs must stay live across the whole loop. Zero runtime cost.
#pragma unroll
    for (int i = 0; i < 32; ++i) {
      f32x4 tmp = __builtin_bit_cast(f32x4, Breg[i]);
      asm volatile("" : "+v"(tmp));
      Breg[i] = __builtin_bit_cast(short8, tmp);
    }

    // Prefetch x-contribution (overlaps the poll).
    unsigned long long zx8;
    if (t < 256) {
      // Encoder Zx rows: agent-scope (cache-bypass) -- overlay safety.
      const size_t xrow = (size_t)(t * 64 + rglob);
      zx8 = __hip_atomic_load((const unsigned long long*)(Zx + xrow * 4096 + Q * 16 + gu * 4),
                              __ATOMIC_RELAXED, __HIP_MEMORY_SCOPE_AGENT);
    } else {
      // Decoder table rows 16384+tok: never overlaid -> normal load.
      const size_t xrow = (size_t)(16384 + tok_tgt[rglob * 256 + (t - 256)]);
      zx8 = *(const unsigned long long*)(Zx + xrow * 4096 + Q * 16 + gu * 4);
    }

    f32x4 acc0 = {0.f, 0.f, 0.f, 0.f};
    f32x4 acc1 = {0.f, 0.f, 0.f, 0.f};
    f32x4 acc2 = {0.f, 0.f, 0.f, 0.f};
    f32x4 acc3 = {0.f, 0.f, 0.f, 0.f};
    if (t > 0) {
      // ---- Flat per-bg barrier: all 64 producers published C_t. ----
      if (wv == 0) {
        int spin = 0;
        for (;;) {
          const int v = __hip_atomic_load(&slot_bg[lane * 32],
                                          __ATOMIC_RELAXED, __HIP_MEMORY_SCOPE_AGENT);
          if (__ballot(v >= t) == ~0ull) break;
          if (++spin > (1 << 18)) break;   // watchdog: garbage beats hang
        }
      }
      COMPILER_FENCE();
      __syncthreads();

      // ---- Stage the whole 32KB h slab into LDS: async global->LDS, no
      // VGPR round-trip, ONE exposed latency. Wave wv stages bytes
      // [wv*8K, wv*8K+8K) in 8 x 1KB pushes (lane x 16B, linear). ----
      {
        const unsigned short* hb = chain_slab(Zx, hbuf1, chainD, t, bg);
        const char* src = (const char*)hb + wv * 8192 + lane * 16;
        char* dst = (char*)hstage + wv * 8192;   // wave-uniform base
#pragma unroll
        for (int r = 0; r < 8; ++r)
          __builtin_amdgcn_global_load_lds(
              (const unsigned int*)(src + r * 1024),
              (unsigned int*)(dst + r * 1024), 16, 0, 0);
      }
      WAIT_VM0();
      __syncthreads();

      // ---- 32 ds_read_b128 A-frags + 32 MFMA (Breg register-resident). ----
#pragma unroll
      for (int kt = 0; kt < 8; ++kt) {
        const short8 a0 = *(const short8*)(lfrag + kt * 512);
        const short8 a1 = *(const short8*)(lfrag + (kt + 8) * 512);
        const short8 a2 = *(const short8*)(lfrag + (kt + 16) * 512);
        const short8 a3 = *(const short8*)(lfrag + (kt + 24) * 512);
        acc0 = MFMA16(a0, Breg[kt], acc0);
        acc1 = MFMA16(a1, Breg[kt + 8], acc1);
        acc2 = MFMA16(a2, Breg[kt + 16], acc2);
        acc3 = MFMA16(a3, Breg[kt + 24], acc3);
      }
    }

    // Transpose through wave-private LDS: C-layout -> (row, unit) lanes.
#pragma unroll
    for (int i = 0; i < 4; ++i)
      zt_w[(q * 4 + i) * 17 + m15] = (acc0[i] + acc1[i]) + (acc2[i] + acc3[i]);
    __builtin_amdgcn_s_waitcnt(0xC07F);   // lgkmcnt(0)
    const float* zr = zt_w + gr * 17 + gu * 4;
    float z0 = zr[0], z1 = zr[1], z2 = zr[2], z3 = zr[3];

    z0 += bf2f((unsigned short)(zx8 >> 0))  + bias0;
    z1 += bf2f((unsigned short)(zx8 >> 16)) + bias1;
    z2 += bf2f((unsigned short)(zx8 >> 32)) + bias2;
    z3 += bf2f((unsigned short)(zx8 >> 48)) + bias3;

    const float ig = sigf(z0);
    const float jg = tanhf_fast(z1);
    const float fg = sigf(z2);
    const float og = sigf(z3);
    cst = fg * cst + ig * jg;
    const float hv = og * tanhf_fast(cst);
    const unsigned short hb16 = f2bf(hv);

    // Producer-major store: wave wv's 4 units for row gr -> 8B at block
    // ug*512B + gr*32B + wv*8B (sole writer of its lines).
    const unsigned int partner = (unsigned int)(unsigned short)__shfl_down((int)hb16, 1);
    const unsigned int hpack = (unsigned int)hb16 | (partner << 16);
    const unsigned int hpack2 = (unsigned int)__shfl_down((int)hpack, 2);
    if (gu == 0) {
      unsigned short* cb = chain_slab(Zx, hbuf1, chainD, t + 1, bg);
      unsigned long long* cq = (unsigned long long*)cb + ug * 64 + gr * 4 + wv;
      const unsigned long long hq =
          (unsigned long long)hpack | ((unsigned long long)hpack2 << 32);
      __hip_atomic_store(cq, hq,
                         __ATOMIC_RELAXED, __HIP_MEMORY_SCOPE_AGENT);
    }

    // Drain own stores, join waves, publish step count.
    COMPILER_FENCE();
    WAIT_VM0();
    COMPILER_FENCE();
    __syncthreads();
    if (tid == 0)
      __hip_atomic_store(&slot_bg[ug * 32], t + 1,
                         __ATOMIC_RELAXED, __HIP_MEMORY_SCOPE_AGENT);
  }
}

// ---------------------------------------------------------------- k4
// Reads decoder h from chainD (producer-major): buffer td = blockIdx.x covers
// batch rows 0..63 (chain c = wv, local row r = m).
__global__ __launch_bounds__(256, 1)
void k4_proj(const unsigned short* __restrict__ hs,   // = chainD
             const unsigned short* __restrict__ WT,   // WprojT [64][1024]
             const float* __restrict__ b_proj,
             float* __restrict__ out)
{
  __shared__ __align__(16) unsigned short Wl[64 * 264];
  __shared__ float zb[4 * 16 * 68];
  const int tid = threadIdx.x;
  const int wv = tid >> 6, lane = tid & 63;
  const int q = lane >> 4, m = lane & 15;
  const int row0 = blockIdx.x * 64 + wv * 16;
  f32x4 acc[4];
#pragma unroll
  for (int nt = 0; nt < 4; ++nt) acc[nt] = (f32x4){0.f, 0.f, 0.f, 0.f};

  // Producer-major A addressing: unit u = kp*256 + kt*32 + q*8 + j ->
  // block pg = kp*16 + 2kt + (q>>1), short offset pg*256 + m*16 + (q&1)*8.
  const unsigned short* abase = hs + (size_t)blockIdx.x * 65536 + wv * 16384
                                + (q >> 1) * 256 + m * 16 + (q & 1) * 8;
  for (int kp = 0; kp < 4; ++kp) {
    __syncthreads();
    for (int i = tid; i < 64 * 32; i += 256) {
      const int n = i >> 5, kc = i & 31;
      *(short8*)(&Wl[n * 264 + kc * 8]) =
          *(const short8*)(WT + (size_t)n * 1024 + kp * 256 + kc * 8);
    }
    __syncthreads();
#pragma unroll 2
    for (int kt = 0; kt < 8; ++kt) {
      const short8 af = *(const short8*)(abase + kp * 4096 + kt * 512);
#pragma unroll
      for (int nt = 0; nt < 4; ++nt) {
        const short8 bfr = *(const short8*)(&Wl[(nt * 16 + m) * 264 + kt * 32 + q * 8]);
        acc[nt] = MFMA16(af, bfr, acc[nt]);
      }
    }
  }
  float* z = &zb[wv * (16 * 68)];
#pragma unroll
  for (int nt = 0; nt < 4; ++nt)
#pragma unroll
    for (int i = 0; i < 4; ++i)
      z[(q * 4 + i) * 68 + nt * 16 + m] = acc[nt][i];
  __syncthreads();
  const int r = lane >> 2, s = lane & 3;
  const float* zrow = z + r * 68 + s * 16;
  float v[16];
  float mx = -1e30f;
#pragma unroll
  for (int j = 0; j < 16; ++j) {
    v[j] = zrow[j] + b_proj[s * 16 + j];
    mx = fmaxf(mx, v[j]);
  }
  mx = fmaxf(mx, __shfl_xor(mx, 1));
  mx = fmaxf(mx, __shfl_xor(mx, 2));
  float sum = 0.f;
#pragma unroll
  for (int j = 0; j < 16; ++j) { v[j] = __expf(v[j] - mx); sum += v[j]; }
  sum += __shfl_xor(sum, 1);
  sum += __shfl_xor(sum, 2);
  const float inv = 1.0f / sum;
  const int nrow = row0 + r;
  const int b = nrow & 63, t = nrow >> 6;
  float* op = out + ((size_t)b * 256 + t) * 64 + s * 16;
#pragma unroll
  for (int x = 0; x < 4; ++x) {
    const float4v o4 = { v[4 * x] * inv, v[4 * x + 1] * inv,
                         v[4 * x + 2] * inv, v[4 * x + 3] * inv };
    *(float4v*)(op + 4 * x) = o4;
  }
}

// ---------------------------------------------------------------- launch
extern "C" void kernel_launch(void* const* d_in, const int* in_sizes, int n_in,
                              void* d_out, int out_size, void* d_ws, size_t ws_size,
                              hipStream_t stream)
{
  const int*   tok_src = (const int*)d_in[0];
  const int*   tok_tgt = (const int*)d_in[1];
  const float* emb_src = (const float*)d_in[2];
  const float* emb_tgt = (const float*)d_in[3];
  const float* W_lstm  = (const float*)d_in[4];
  const float* b_lstm  = (const float*)d_in[5];
  const float* W_proj  = (const float*)d_in[6];
  const float* b_proj  = (const float*)d_in[7];
  float* out = (float*)d_out;

  char* ws = (char*)d_ws;
  size_t off = 0;
  const size_t slot_bytes = (size_t)4 * 64 * 128;      // 128B line per (bg,ug)
  int* slot             = (int*)(ws + off);            off += slot_bytes;
  unsigned short* A     = (unsigned short*)(ws + off); off += (size_t)16512 * 512 * 2;
  unsigned short* WT    = (unsigned short*)(ws + off); off += (size_t)4096 * 1536 * 2;
  unsigned short* WPT   = (unsigned short*)(ws + off); off += (size_t)64 * 1024 * 2;
  unsigned short* Zx    = (unsigned short*)(ws + off); off += (size_t)16512 * 4096 * 2;
  unsigned short* hbuf1 = (unsigned short*)(ws + off); off += (size_t)64 * 1024 * 2;
  unsigned short* chainD= (unsigned short*)(ws + off); off += (size_t)256 * 64 * 1024 * 2;
  if (ws_size < off) return;  // insufficient workspace -> loud correctness failure

  hipMemsetAsync(slot, 0, slot_bytes, stream);
  hipLaunchKernelGGL(k1a_gather, dim3(16512), dim3(128), 0, stream, tok_src, emb_src, emb_tgt, A);
  hipLaunchKernelGGL(k1w_perm,   dim3(3072),  dim3(256), 0, stream, W_lstm, WT);
  hipLaunchKernelGGL(k1p_perm,   dim3(32),    dim3(256), 0, stream, W_proj, WPT);
  hipLaunchKernelGGL(k2_gemm,    dim3(32, 129), dim3(256), 0, stream, A, WT, Zx);
  hipLaunchKernelGGL(k3_rnn,     dim3(256),   dim3(256), 0, stream, Zx, WT, b_lstm, tok_tgt, hbuf1, chainD, slot);
  hipLaunchKernelGGL(k4_proj,    dim3(256),   dim3(256), 0, stream, chainD, WPT, b_proj, out);
}